// Round 21
// baseline (157.594 us; speedup 1.0000x reference)
//
#include <hip/hip_runtime.h>
#include <hip/hip_fp16.h>

// Op: out = (1/num_op) * sum_i ws[i] * SpMM(A_i, x).
// Pipeline: [x->f16 | bucket count] merged | scan | bucketed scatter
//           (vec4 edge loads, reg-cached rows) | per-bucket (row,colseg) sort
//           -> 4B records + binoff | all-resident seg-phased lockstep gather,
//           1 bucket per 256-thr block, chained bounds, 16-deep ILP, CSEG=4,
//           x in f16 -> v_fma_mix_f32 (no unpack VALU).
// N=50000, D=128, NUM_OP=8, E=400000.

#define D_DIM 128
#define RPB_SHIFT 5
#define RPB 32
#define CSEG 4
#define CSEG_SHIFT 14          // col>>14 : 50000>>14 = 3 < 4 segs
#define NB (RPB * CSEG)        // 128 sort bins per bucket (~16 records/bin)
#define MAXB 2048
#define CHUNK 8192
#define SCAN_BLOCK 1024
#define CVT_BLOCKS 1024
#define CNT_BLOCKS 256

typedef unsigned long long ull;

static __device__ __forceinline__ unsigned short f2bf(float f) {
    unsigned int u = __float_as_uint(f);
    u += 0x7FFFu + ((u >> 16) & 1u);          // round-to-nearest-even
    return (unsigned short)(u >> 16);
}

static __device__ __forceinline__ unsigned short f2h(float f) {
    return __half_as_ushort(__float2half(f));  // f32 -> f16 (RTN)
}

static __device__ __forceinline__ ull pack2f(float a, float b) {
    return (ull)__float_as_uint(a) | ((ull)__float_as_uint(b) << 32);
}

// ---------- fallback (round-0) atomic scatter kernel ----------
__global__ __launch_bounds__(256) void spmm_scatter_kernel(
    const float* __restrict__ x, const float* __restrict__ edge_vals,
    const float* __restrict__ ws, const int* __restrict__ edge_rows,
    const int* __restrict__ edge_cols, float* __restrict__ out,
    int E, float inv_num)
{
    const int  op   = blockIdx.y;
    const long base = (long)op * (long)E;
    const float wscale = ws[op] * inv_num;
    const int lane = threadIdx.x & 63;
    const int wave = blockIdx.x * (blockDim.x >> 6) + (threadIdx.x >> 6);
    const int nwaves = gridDim.x * (blockDim.x >> 6);
    for (int e = wave; e < E; e += nwaves) {
        const int row = edge_rows[base + e];
        const int col = edge_cols[base + e];
        const float v = edge_vals[base + e] * wscale;
        const float2 xv = *reinterpret_cast<const float2*>(x + (long)col * D_DIM + lane * 2);
        float* o = out + (long)row * D_DIM + lane * 2;
        atomicAdd(o, xv.x * v);
        atomicAdd(o + 1, xv.y * v);
    }
}

// ---------- 0+1. merged: x->f16 convert | coarse bucket count (vec4) ----------
__global__ __launch_bounds__(256) void convert_count_kernel(
    const float4* __restrict__ x4, ull* __restrict__ xh, int n4,
    const int* __restrict__ rows, int* __restrict__ gcount, long n, int B)
{
    __shared__ int h[MAXB];
    if (blockIdx.x < CVT_BLOCKS) {
        const int stride = CVT_BLOCKS * 256;
        for (int i = blockIdx.x * 256 + threadIdx.x; i < n4; i += stride) {
            const float4 v = x4[i];
            const ull p =
                (ull)f2h(v.x)
                | ((ull)f2h(v.y) << 16)
                | ((ull)f2h(v.z) << 32)
                | ((ull)f2h(v.w) << 48);
            xh[i] = p;
        }
    } else {
        const int cb = blockIdx.x - CVT_BLOCKS;
        for (int i = threadIdx.x; i < B; i += 256) h[i] = 0;
        __syncthreads();
        const long n4r = n >> 2;
        for (long q = (long)cb * 256 + threadIdx.x; q < n4r;
             q += (long)CNT_BLOCKS * 256) {
            const int4 r = reinterpret_cast<const int4*>(rows)[q];
            atomicAdd(&h[r.x >> RPB_SHIFT], 1);
            atomicAdd(&h[r.y >> RPB_SHIFT], 1);
            atomicAdd(&h[r.z >> RPB_SHIFT], 1);
            atomicAdd(&h[r.w >> RPB_SHIFT], 1);
        }
        if (cb == 0 && (long)threadIdx.x < (n & 3))
            atomicAdd(&h[rows[(n4r << 2) + threadIdx.x] >> RPB_SHIFT], 1);
        __syncthreads();
        for (int i = threadIdx.x; i < B; i += 256)
            if (h[i]) atomicAdd(&gcount[i], h[i]);
    }
}

// ---------- 2. exclusive scan (single block, proven multi-tile) ----------
__global__ __launch_bounds__(SCAN_BLOCK) void scan_kernel(
    int* __restrict__ cursors, int* __restrict__ offsets, int N)
{
    __shared__ int sdata[SCAN_BLOCK];
    __shared__ int carry_s;
    if (threadIdx.x == 0) carry_s = 0;
    __syncthreads();
    for (int base = 0; base < N; base += SCAN_BLOCK) {
        const int i = base + (int)threadIdx.x;
        const int v = (i < N) ? cursors[i] : 0;
        sdata[threadIdx.x] = v;
        __syncthreads();
        for (int ofs = 1; ofs < SCAN_BLOCK; ofs <<= 1) {
            int t = (threadIdx.x >= (unsigned)ofs) ? sdata[threadIdx.x - ofs] : 0;
            __syncthreads();
            sdata[threadIdx.x] += t;
            __syncthreads();
        }
        const int incl  = sdata[threadIdx.x];
        const int carry = carry_s;
        if (i < N) {
            const int excl = carry + incl - v;
            offsets[i] = excl;
            cursors[i] = excl;
        }
        __syncthreads();
        if (threadIdx.x == SCAN_BLOCK - 1) carry_s = carry + incl;
        __syncthreads();
    }
    if (threadIdx.x == 0) offsets[N] = carry_s;
}

// ---------- 3. bucketed scatter: vec4 loads, reg-cached rows ----------
__global__ __launch_bounds__(1024, 8) void scatter_bucket_kernel(
    const int* __restrict__ edge_rows, const int* __restrict__ edge_cols,
    const float* __restrict__ edge_vals, const float* __restrict__ ws,
    int* __restrict__ gcursor, ull* __restrict__ records,
    int E, float inv_num, int B)
{
    __shared__ int hist[MAXB];                 // counts, then global-base cursors
    const int  op   = blockIdx.y;
    const long base = (long)op * (long)E;
    const int  e0   = blockIdx.x * CHUNK;
    const int  e1   = min(e0 + CHUNK, E);
    const float wscale = ws[op] * inv_num;
    const int  tid  = (int)threadIdx.x;
    const int*   erow = edge_rows + base;
    const int*   ecol = edge_cols + base;
    const float* eval = edge_vals + base;

    for (int i = tid; i < B; i += 1024) hist[i] = 0;
    __syncthreads();

    // this thread's 8 edges: two contiguous groups of 4 (coalesced int4)
    const int gA = e0 + tid * 4;
    const int gB = gA + 4096;                  // CHUNK/2
    int4 rA = make_int4(0, 0, 0, 0), rB = make_int4(0, 0, 0, 0);
    int  mA = 0, mB = 0;

    { const int rem = e1 - gA;
      if (rem >= 4) { rA = *reinterpret_cast<const int4*>(erow + gA); mA = 4; }
      else if (rem > 0) { mA = rem; rA.x = erow[gA];
          if (rem > 1) rA.y = erow[gA + 1];
          if (rem > 2) rA.z = erow[gA + 2]; } }
    { const int rem = e1 - gB;
      if (rem >= 4) { rB = *reinterpret_cast<const int4*>(erow + gB); mB = 4; }
      else if (rem > 0) { mB = rem; rB.x = erow[gB];
          if (rem > 1) rB.y = erow[gB + 1];
          if (rem > 2) rB.z = erow[gB + 2]; } }

    if (mA > 0) atomicAdd(&hist[rA.x >> RPB_SHIFT], 1);
    if (mA > 1) atomicAdd(&hist[rA.y >> RPB_SHIFT], 1);
    if (mA > 2) atomicAdd(&hist[rA.z >> RPB_SHIFT], 1);
    if (mA > 3) atomicAdd(&hist[rA.w >> RPB_SHIFT], 1);
    if (mB > 0) atomicAdd(&hist[rB.x >> RPB_SHIFT], 1);
    if (mB > 1) atomicAdd(&hist[rB.y >> RPB_SHIFT], 1);
    if (mB > 2) atomicAdd(&hist[rB.z >> RPB_SHIFT], 1);
    if (mB > 3) atomicAdd(&hist[rB.w >> RPB_SHIFT], 1);
    __syncthreads();

    for (int i = tid; i < B; i += 1024) {
        const int c = hist[i];
        hist[i] = c ? atomicAdd(&gcursor[i], c) : 0;   // reserve run, one atomic/bin
    }
    __syncthreads();

#define EMIT(RW, CW, VW)                                                       \
    { const int bin_ = (RW) >> RPB_SHIFT;                                      \
      const int pos_ = atomicAdd(&hist[bin_], 1);                              \
      const ull rec_ = ((ull)__float_as_uint((VW) * wscale) << 32)             \
          | ((unsigned int)((RW) & (RPB - 1)) << 16) | (unsigned int)(CW);     \
      records[pos_] = rec_; }

    if (mA > 0) {
        int4 c = make_int4(0, 0, 0, 0); float4 v = make_float4(0.f, 0.f, 0.f, 0.f);
        if (mA == 4) { c = *reinterpret_cast<const int4*>(ecol + gA);
                       v = *reinterpret_cast<const float4*>(eval + gA); }
        else { c.x = ecol[gA]; v.x = eval[gA];
               if (mA > 1) { c.y = ecol[gA + 1]; v.y = eval[gA + 1]; }
               if (mA > 2) { c.z = ecol[gA + 2]; v.z = eval[gA + 2]; } }
        EMIT(rA.x, c.x, v.x)
        if (mA > 1) EMIT(rA.y, c.y, v.y)
        if (mA > 2) EMIT(rA.z, c.z, v.z)
        if (mA > 3) EMIT(rA.w, c.w, v.w)
    }
    if (mB > 0) {
        int4 c = make_int4(0, 0, 0, 0); float4 v = make_float4(0.f, 0.f, 0.f, 0.f);
        if (mB == 4) { c = *reinterpret_cast<const int4*>(ecol + gB);
                       v = *reinterpret_cast<const float4*>(eval + gB); }
        else { c.x = ecol[gB]; v.x = eval[gB];
               if (mB > 1) { c.y = ecol[gB + 1]; v.y = eval[gB + 1]; }
               if (mB > 2) { c.z = ecol[gB + 2]; v.z = eval[gB + 2]; } }
        EMIT(rB.x, c.x, v.x)
        if (mB > 1) EMIT(rB.y, c.y, v.y)
        if (mB > 2) EMIT(rB.z, c.z, v.z)
        if (mB > 3) EMIT(rB.w, c.w, v.w)
    }
#undef EMIT
}

// ---------- 3b. per-bucket (row,colseg) sort -> 4B records + binoff ----------
// 512 threads = 8 waves; NB=128 bins (tid<128 scans, 2 waves); shfl wave-scan.
// bin = rl*CSEG + seg  (rl-major, matches gather's bb + rr*CSEG + seg)
__global__ __launch_bounds__(512) void sort_bucket_kernel(
    const ull* __restrict__ records, unsigned int* __restrict__ sorted32,
    const int* __restrict__ boff, int* __restrict__ binoff, int N, int B)
{
    __shared__ int h[NB];
    __shared__ int cur[NB];
    __shared__ int wsum[2];
    __shared__ int woff[2];
    const int bkt   = blockIdx.x;
    const int start = boff[bkt], end = boff[bkt + 1];
    const int tid   = (int)threadIdx.x;
    const int lane  = tid & 63;
    const int w     = tid >> 6;

    if (tid < NB) h[tid] = 0;
    __syncthreads();
    for (int i = start + tid; i < end; i += 512) {
        const unsigned int lo = (unsigned int)records[i];
        const int bin = (int)((lo >> 16) << 2) | (int)((lo & 0xFFFFu) >> CSEG_SHIFT);
        atomicAdd(&h[bin], 1);
    }
    __syncthreads();
    // wave-level inclusive scan of this thread's bin (bin == tid), tid < 128
    if (tid < NB) {
        const int v = h[tid];
        int incl = v;
        #pragma unroll
        for (int o = 1; o < 64; o <<= 1) {
            const int t = __shfl_up(incl, o);
            if (lane >= o) incl += t;
        }
        if (lane == 63) wsum[w] = incl;
        __syncthreads();
        if (tid == 0) { woff[0] = 0; woff[1] = wsum[0]; }
        __syncthreads();
        const int excl = start + woff[w] + incl - v;
        cur[tid] = excl;
        binoff[bkt * NB + tid] = excl;
    } else {
        __syncthreads();
        __syncthreads();
    }
    if (tid == 0 && bkt == B - 1) binoff[B * NB] = end;
    __syncthreads();
    for (int i = start + tid; i < end; i += 512) {
        const ull r = records[i];
        const unsigned int lo = (unsigned int)r;
        const int bin = (int)((lo >> 16) << 2) | (int)((lo & 0xFFFFu) >> CSEG_SHIFT);
        const int pos = atomicAdd(&cur[bin], 1);
        // 4B record: col (lo16) | bf16(val) (hi16)
        sorted32[pos] = (lo & 0xFFFFu)
            | ((unsigned int)f2bf(__uint_as_float((unsigned int)(r >> 32))) << 16);
    }
}

// ---------- 4. gather: lockstep sweep, 1 bucket per 256-thr block ----------
// grid = B blocks x 256 thr (4 waves); wave owns 8 rows; 4-seg outer loop;
// chained bounds + batched prefetch + 16-deep ILP; x in f16 -> v_fma_mix.
#define GREC(RK)                                                               \
    { const unsigned int p_ = *reinterpret_cast<const unsigned int*>(          \
          xh + (size_t)((RK)&0xFFFFu) * D_DIM + lane * 2);                     \
      const float v_ = __uint_as_float((RK)&0xFFFF0000u);                      \
      const __half2 h2_ = *reinterpret_cast<const __half2*>(&p_);              \
      ax += v_ * __half2float(h2_.x);                                          \
      ay += v_ * __half2float(h2_.y); }

__global__ __launch_bounds__(256) void gather_seg_kernel(
    const unsigned short* __restrict__ xh, const int* __restrict__ binoff,
    const unsigned int* __restrict__ sorted32, float* __restrict__ out,
    int N, int B)
{
    const int tid  = (int)threadIdx.x;
    const int lane = tid & 63;
    const int w    = tid >> 6;                     // 0..3
    const int bkt  = blockIdx.x;
    const int rl0  = w * 8;                        // first of this wave's 8 rows
    const int bb   = bkt * NB + rl0 * CSEG;        // binoff base for row rl0

    float accx[8], accy[8];
    int jcur[8];
    #pragma unroll
    for (int rr = 0; rr < 8; ++rr) {
        accx[rr] = 0.f; accy[rr] = 0.f;
        jcur[rr] = __builtin_amdgcn_readfirstlane(binoff[bb + rr * CSEG]);
    }

    for (int seg = 0; seg < CSEG; ++seg) {
        int jend[8];
        #pragma unroll
        for (int rr = 0; rr < 8; ++rr)             // 8 independent bound loads
            jend[rr] = __builtin_amdgcn_readfirstlane(
                binoff[bb + rr * CSEG + seg + 1]);
        #pragma unroll
        for (int rr = 0; rr < 8; ++rr) {
            int j = jcur[rr];
            const int je = jend[rr];
            float ax = accx[rr], ay = accy[rr];
            for (; j + 15 < je; j += 16) {         // 16 x-loads in flight: 1 bin
                const unsigned int r0  = sorted32[j];
                const unsigned int r1  = sorted32[j + 1];
                const unsigned int r2  = sorted32[j + 2];
                const unsigned int r3  = sorted32[j + 3];
                const unsigned int r4  = sorted32[j + 4];
                const unsigned int r5  = sorted32[j + 5];
                const unsigned int r6  = sorted32[j + 6];
                const unsigned int r7  = sorted32[j + 7];
                const unsigned int r8  = sorted32[j + 8];
                const unsigned int r9  = sorted32[j + 9];
                const unsigned int r10 = sorted32[j + 10];
                const unsigned int r11 = sorted32[j + 11];
                const unsigned int r12 = sorted32[j + 12];
                const unsigned int r13 = sorted32[j + 13];
                const unsigned int r14 = sorted32[j + 14];
                const unsigned int r15 = sorted32[j + 15];
                GREC(r0)  GREC(r1)  GREC(r2)  GREC(r3)
                GREC(r4)  GREC(r5)  GREC(r6)  GREC(r7)
                GREC(r8)  GREC(r9)  GREC(r10) GREC(r11)
                GREC(r12) GREC(r13) GREC(r14) GREC(r15)
            }
            if (j + 7 < je) {                      // 8-deep remainder
                const unsigned int r0 = sorted32[j];
                const unsigned int r1 = sorted32[j + 1];
                const unsigned int r2 = sorted32[j + 2];
                const unsigned int r3 = sorted32[j + 3];
                const unsigned int r4 = sorted32[j + 4];
                const unsigned int r5 = sorted32[j + 5];
                const unsigned int r6 = sorted32[j + 6];
                const unsigned int r7 = sorted32[j + 7];
                GREC(r0) GREC(r1) GREC(r2) GREC(r3)
                GREC(r4) GREC(r5) GREC(r6) GREC(r7)
                j += 8;
            }
            if (j + 3 < je) {                      // 4-deep remainder
                const unsigned int r0 = sorted32[j];
                const unsigned int r1 = sorted32[j + 1];
                const unsigned int r2 = sorted32[j + 2];
                const unsigned int r3 = sorted32[j + 3];
                GREC(r0) GREC(r1) GREC(r2) GREC(r3)
                j += 4;
            }
            if (j + 1 < je) {                      // 2-deep remainder
                const unsigned int r0 = sorted32[j];
                const unsigned int r1 = sorted32[j + 1];
                GREC(r0) GREC(r1)
                j += 2;
            }
            if (j < je) {
                const unsigned int r0 = sorted32[j];
                GREC(r0)
            }
            accx[rr] = ax; accy[rr] = ay;
            jcur[rr] = je;                         // chain: next seg starts here
        }
    }

    const int row0 = (bkt << RPB_SHIFT) + rl0;
    #pragma unroll
    for (int rr = 0; rr < 8; ++rr) {
        const int row = row0 + rr;
        if (row < N)
            __builtin_nontemporal_store(pack2f(accx[rr], accy[rr]),
                reinterpret_cast<ull*>(out + (size_t)row * D_DIM + lane * 2));
    }
}

// ---------- 4-alt (round-7 proven, f16 x): ballot-filter gather ----------
__global__ __launch_bounds__(1024) void gather_filter2_kernel(
    const unsigned short* __restrict__ xh, const int* __restrict__ boff,
    const ull* __restrict__ records, float* __restrict__ out, int N)
{
    const int lane = threadIdx.x & 63;
    const int wv   = threadIdx.x >> 6;
    const int bkt  = blockIdx.x;
    const int row0 = (bkt << RPB_SHIFT) + wv * 2;
    const int row1 = row0 + 1;
    const int start = boff[bkt], end = boff[bkt + 1];

    float a0x = 0.f, a0y = 0.f, a1x = 0.f, a1y = 0.f;
    for (int c = start; c < end; c += 64) {
        const int idx = c + lane;
        unsigned int lo = 0xFFFF0000u, hi = 0;
        if (idx < end) {
            const ull r = __builtin_nontemporal_load(&records[idx]);
            lo = (unsigned int)r;
            hi = (unsigned int)(r >> 32);
        }
        ull mask = __ballot((lo >> 17) == (unsigned int)wv);
        while (mask) {
            const int j = __ffsll(mask) - 1;
            mask &= mask - 1;
            const unsigned int lj = __shfl(lo, j);
            const float v = __uint_as_float(__shfl(hi, j));
            const unsigned int col = lj & 0xFFFFu;
            const unsigned int p = *reinterpret_cast<const unsigned int*>(
                xh + (size_t)col * D_DIM + lane * 2);
            const __half2 h2 = *reinterpret_cast<const __half2*>(&p);
            const float px = __half2float(h2.x);
            const float py = __half2float(h2.y);
            if (lj & 0x10000u) { a1x += v * px; a1y += v * py; }
            else               { a0x += v * px; a0y += v * py; }
        }
    }
    if (row0 < N)
        __builtin_nontemporal_store(pack2f(a0x, a0y),
            reinterpret_cast<ull*>(out + (size_t)row0 * D_DIM + lane * 2));
    if (row1 < N)
        __builtin_nontemporal_store(pack2f(a1x, a1y),
            reinterpret_cast<ull*>(out + (size_t)row1 * D_DIM + lane * 2));
}

extern "C" void kernel_launch(void* const* d_in, const int* in_sizes, int n_in,
                              void* d_out, int out_size, void* d_ws, size_t ws_size,
                              hipStream_t stream)
{
    const float* x         = (const float*)d_in[0];
    const float* edge_vals = (const float*)d_in[1];
    const float* ws        = (const float*)d_in[2];
    const int*   edge_rows = (const int*)d_in[3];
    const int*   edge_cols = (const int*)d_in[4];
    float*       out       = (float*)d_out;

    const int num_op = in_sizes[2];               // 8
    const int E      = in_sizes[1] / num_op;      // 400000
    const int N      = in_sizes[0] / D_DIM;       // 50000
    const long Etot  = (long)num_op * (long)E;    // 3.2M
    const int  B     = (N + RPB - 1) / RPB;       // 1563 buckets
    const float inv_num = 1.0f / (float)num_op;

    // workspace: boff | gcursor | binoff | xh | records | sorted32
    const size_t off_boff    = 0;
    const size_t off_gcur    = ((size_t)(B + 1) * 4 + 255) & ~(size_t)255;
    const size_t off_binoff  = (off_gcur + (size_t)B * 4 + 255) & ~(size_t)255;
    const size_t off_xh      = (off_binoff + ((size_t)B * NB + 1) * 4 + 255) & ~(size_t)255;
    const size_t off_records = (off_xh + (size_t)N * D_DIM * 2 + 255) & ~(size_t)255;
    const size_t off_sorted  = off_records + (size_t)Etot * 8;
    const size_t need_sort   = off_sorted + (size_t)Etot * 4;
    const size_t need_filter = off_sorted;        // without the sorted32 buffer

    if (ws_size < need_filter || B > MAXB || N > 65535) {
        (void)hipMemsetAsync(d_out, 0, (size_t)out_size * sizeof(float), stream);
        dim3 grid(256, num_op, 1);
        spmm_scatter_kernel<<<grid, 256, 0, stream>>>(
            x, edge_vals, ws, edge_rows, edge_cols, out, E, inv_num);
        return;
    }

    int* boff    = (int*)((char*)d_ws + off_boff);
    int* gcursor = (int*)((char*)d_ws + off_gcur);
    int* binoff  = (int*)((char*)d_ws + off_binoff);
    unsigned short* xh = (unsigned short*)((char*)d_ws + off_xh);
    ull* records = (ull*)((char*)d_ws + off_records);
    unsigned int* sorted32 = (unsigned int*)((char*)d_ws + off_sorted);

    (void)hipMemsetAsync(gcursor, 0, (size_t)B * 4, stream);

    convert_count_kernel<<<CVT_BLOCKS + CNT_BLOCKS, 256, 0, stream>>>(
        (const float4*)x, (ull*)xh, N * D_DIM / 4, edge_rows, gcursor, Etot, B);
    scan_kernel<<<1, SCAN_BLOCK, 0, stream>>>(gcursor, boff, B);

    dim3 sgrid((E + CHUNK - 1) / CHUNK, num_op, 1);   // 49 x 8 = 392 blocks, 16 waves
    scatter_bucket_kernel<<<sgrid, 1024, 0, stream>>>(
        edge_rows, edge_cols, edge_vals, ws, gcursor, records, E, inv_num, B);

    if (ws_size >= need_sort) {
        sort_bucket_kernel<<<B, 512, 0, stream>>>(
            records, sorted32, boff, binoff, N, B);
        gather_seg_kernel<<<B, 256, 0, stream>>>(
            xh, binoff, sorted32, out, N, B);
    } else {
        gather_filter2_kernel<<<B, 1024, 0, stream>>>(xh, boff, records, out, N);
    }
}

// Round 22
// 156.369 us; speedup vs baseline: 1.0078x; 1.0078x over previous
//
#include <hip/hip_runtime.h>
#include <hip/hip_fp16.h>

// Op: out = (1/num_op) * sum_i ws[i] * SpMM(A_i, x).
// Pipeline: [x->f16 | bucket count] merged | scan | bucketed scatter
//           (vec4 edge loads, reg-cached rows) | FUSED per-bucket
//           {(row,colseg) sort into LDS -> lockstep seg-major gather},
//           512 thr = 8 waves x 4 rows, 16-deep ILP, CSEG=4.
// N=50000, D=128, NUM_OP=8, E=400000.

#define D_DIM 128
#define RPB_SHIFT 5
#define RPB 32
#define CSEG 4
#define CSEG_SHIFT 14          // col>>14 : 50000>>14 = 3 < 4 segs
#define NB (RPB * CSEG)        // 128 sort bins per bucket (~16 records/bin)
#define LREC_CAP 4096          // LDS record capacity (mean 2048, 45-sigma safe)
#define MAXB 2048
#define CHUNK 8192
#define SCAN_BLOCK 1024
#define CVT_BLOCKS 1024
#define CNT_BLOCKS 256

typedef unsigned long long ull;

static __device__ __forceinline__ unsigned short f2bf(float f) {
    unsigned int u = __float_as_uint(f);
    u += 0x7FFFu + ((u >> 16) & 1u);          // round-to-nearest-even
    return (unsigned short)(u >> 16);
}

static __device__ __forceinline__ unsigned short f2h(float f) {
    return __half_as_ushort(__float2half(f));  // f32 -> f16 (RTN)
}

static __device__ __forceinline__ ull pack2f(float a, float b) {
    return (ull)__float_as_uint(a) | ((ull)__float_as_uint(b) << 32);
}

// ---------- fallback (round-0) atomic scatter kernel ----------
__global__ __launch_bounds__(256) void spmm_scatter_kernel(
    const float* __restrict__ x, const float* __restrict__ edge_vals,
    const float* __restrict__ ws, const int* __restrict__ edge_rows,
    const int* __restrict__ edge_cols, float* __restrict__ out,
    int E, float inv_num)
{
    const int  op   = blockIdx.y;
    const long base = (long)op * (long)E;
    const float wscale = ws[op] * inv_num;
    const int lane = threadIdx.x & 63;
    const int wave = blockIdx.x * (blockDim.x >> 6) + (threadIdx.x >> 6);
    const int nwaves = gridDim.x * (blockDim.x >> 6);
    for (int e = wave; e < E; e += nwaves) {
        const int row = edge_rows[base + e];
        const int col = edge_cols[base + e];
        const float v = edge_vals[base + e] * wscale;
        const float2 xv = *reinterpret_cast<const float2*>(x + (long)col * D_DIM + lane * 2);
        float* o = out + (long)row * D_DIM + lane * 2;
        atomicAdd(o, xv.x * v);
        atomicAdd(o + 1, xv.y * v);
    }
}

// ---------- 0+1. merged: x->f16 convert | coarse bucket count (vec4) ----------
__global__ __launch_bounds__(256) void convert_count_kernel(
    const float4* __restrict__ x4, ull* __restrict__ xh, int n4,
    const int* __restrict__ rows, int* __restrict__ gcount, long n, int B)
{
    __shared__ int h[MAXB];
    if (blockIdx.x < CVT_BLOCKS) {
        const int stride = CVT_BLOCKS * 256;
        for (int i = blockIdx.x * 256 + threadIdx.x; i < n4; i += stride) {
            const float4 v = x4[i];
            const ull p =
                (ull)f2h(v.x)
                | ((ull)f2h(v.y) << 16)
                | ((ull)f2h(v.z) << 32)
                | ((ull)f2h(v.w) << 48);
            xh[i] = p;
        }
    } else {
        const int cb = blockIdx.x - CVT_BLOCKS;
        for (int i = threadIdx.x; i < B; i += 256) h[i] = 0;
        __syncthreads();
        const long n4r = n >> 2;
        for (long q = (long)cb * 256 + threadIdx.x; q < n4r;
             q += (long)CNT_BLOCKS * 256) {
            const int4 r = reinterpret_cast<const int4*>(rows)[q];
            atomicAdd(&h[r.x >> RPB_SHIFT], 1);
            atomicAdd(&h[r.y >> RPB_SHIFT], 1);
            atomicAdd(&h[r.z >> RPB_SHIFT], 1);
            atomicAdd(&h[r.w >> RPB_SHIFT], 1);
        }
        if (cb == 0 && (long)threadIdx.x < (n & 3))
            atomicAdd(&h[rows[(n4r << 2) + threadIdx.x] >> RPB_SHIFT], 1);
        __syncthreads();
        for (int i = threadIdx.x; i < B; i += 256)
            if (h[i]) atomicAdd(&gcount[i], h[i]);
    }
}

// ---------- 2. exclusive scan (single block, proven multi-tile) ----------
__global__ __launch_bounds__(SCAN_BLOCK) void scan_kernel(
    int* __restrict__ cursors, int* __restrict__ offsets, int N)
{
    __shared__ int sdata[SCAN_BLOCK];
    __shared__ int carry_s;
    if (threadIdx.x == 0) carry_s = 0;
    __syncthreads();
    for (int base = 0; base < N; base += SCAN_BLOCK) {
        const int i = base + (int)threadIdx.x;
        const int v = (i < N) ? cursors[i] : 0;
        sdata[threadIdx.x] = v;
        __syncthreads();
        for (int ofs = 1; ofs < SCAN_BLOCK; ofs <<= 1) {
            int t = (threadIdx.x >= (unsigned)ofs) ? sdata[threadIdx.x - ofs] : 0;
            __syncthreads();
            sdata[threadIdx.x] += t;
            __syncthreads();
        }
        const int incl  = sdata[threadIdx.x];
        const int carry = carry_s;
        if (i < N) {
            const int excl = carry + incl - v;
            offsets[i] = excl;
            cursors[i] = excl;
        }
        __syncthreads();
        if (threadIdx.x == SCAN_BLOCK - 1) carry_s = carry + incl;
        __syncthreads();
    }
    if (threadIdx.x == 0) offsets[N] = carry_s;
}

// ---------- 3. bucketed scatter: vec4 loads, reg-cached rows ----------
__global__ __launch_bounds__(1024, 8) void scatter_bucket_kernel(
    const int* __restrict__ edge_rows, const int* __restrict__ edge_cols,
    const float* __restrict__ edge_vals, const float* __restrict__ ws,
    int* __restrict__ gcursor, ull* __restrict__ records,
    int E, float inv_num, int B)
{
    __shared__ int hist[MAXB];                 // counts, then global-base cursors
    const int  op   = blockIdx.y;
    const long base = (long)op * (long)E;
    const int  e0   = blockIdx.x * CHUNK;
    const int  e1   = min(e0 + CHUNK, E);
    const float wscale = ws[op] * inv_num;
    const int  tid  = (int)threadIdx.x;
    const int*   erow = edge_rows + base;
    const int*   ecol = edge_cols + base;
    const float* eval = edge_vals + base;

    for (int i = tid; i < B; i += 1024) hist[i] = 0;
    __syncthreads();

    // this thread's 8 edges: two contiguous groups of 4 (coalesced int4)
    const int gA = e0 + tid * 4;
    const int gB = gA + 4096;                  // CHUNK/2
    int4 rA = make_int4(0, 0, 0, 0), rB = make_int4(0, 0, 0, 0);
    int  mA = 0, mB = 0;

    { const int rem = e1 - gA;
      if (rem >= 4) { rA = *reinterpret_cast<const int4*>(erow + gA); mA = 4; }
      else if (rem > 0) { mA = rem; rA.x = erow[gA];
          if (rem > 1) rA.y = erow[gA + 1];
          if (rem > 2) rA.z = erow[gA + 2]; } }
    { const int rem = e1 - gB;
      if (rem >= 4) { rB = *reinterpret_cast<const int4*>(erow + gB); mB = 4; }
      else if (rem > 0) { mB = rem; rB.x = erow[gB];
          if (rem > 1) rB.y = erow[gB + 1];
          if (rem > 2) rB.z = erow[gB + 2]; } }

    if (mA > 0) atomicAdd(&hist[rA.x >> RPB_SHIFT], 1);
    if (mA > 1) atomicAdd(&hist[rA.y >> RPB_SHIFT], 1);
    if (mA > 2) atomicAdd(&hist[rA.z >> RPB_SHIFT], 1);
    if (mA > 3) atomicAdd(&hist[rA.w >> RPB_SHIFT], 1);
    if (mB > 0) atomicAdd(&hist[rB.x >> RPB_SHIFT], 1);
    if (mB > 1) atomicAdd(&hist[rB.y >> RPB_SHIFT], 1);
    if (mB > 2) atomicAdd(&hist[rB.z >> RPB_SHIFT], 1);
    if (mB > 3) atomicAdd(&hist[rB.w >> RPB_SHIFT], 1);
    __syncthreads();

    for (int i = tid; i < B; i += 1024) {
        const int c = hist[i];
        hist[i] = c ? atomicAdd(&gcursor[i], c) : 0;   // reserve run, one atomic/bin
    }
    __syncthreads();

#define EMIT(RW, CW, VW)                                                       \
    { const int bin_ = (RW) >> RPB_SHIFT;                                      \
      const int pos_ = atomicAdd(&hist[bin_], 1);                              \
      const ull rec_ = ((ull)__float_as_uint((VW) * wscale) << 32)             \
          | ((unsigned int)((RW) & (RPB - 1)) << 16) | (unsigned int)(CW);     \
      records[pos_] = rec_; }

    if (mA > 0) {
        int4 c = make_int4(0, 0, 0, 0); float4 v = make_float4(0.f, 0.f, 0.f, 0.f);
        if (mA == 4) { c = *reinterpret_cast<const int4*>(ecol + gA);
                       v = *reinterpret_cast<const float4*>(eval + gA); }
        else { c.x = ecol[gA]; v.x = eval[gA];
               if (mA > 1) { c.y = ecol[gA + 1]; v.y = eval[gA + 1]; }
               if (mA > 2) { c.z = ecol[gA + 2]; v.z = eval[gA + 2]; } }
        EMIT(rA.x, c.x, v.x)
        if (mA > 1) EMIT(rA.y, c.y, v.y)
        if (mA > 2) EMIT(rA.z, c.z, v.z)
        if (mA > 3) EMIT(rA.w, c.w, v.w)
    }
    if (mB > 0) {
        int4 c = make_int4(0, 0, 0, 0); float4 v = make_float4(0.f, 0.f, 0.f, 0.f);
        if (mB == 4) { c = *reinterpret_cast<const int4*>(ecol + gB);
                       v = *reinterpret_cast<const float4*>(eval + gB); }
        else { c.x = ecol[gB]; v.x = eval[gB];
               if (mB > 1) { c.y = ecol[gB + 1]; v.y = eval[gB + 1]; }
               if (mB > 2) { c.z = ecol[gB + 2]; v.z = eval[gB + 2]; } }
        EMIT(rB.x, c.x, v.x)
        if (mB > 1) EMIT(rB.y, c.y, v.y)
        if (mB > 2) EMIT(rB.z, c.z, v.z)
        if (mB > 3) EMIT(rB.w, c.w, v.w)
    }
#undef EMIT
}

// ---------- 4. FUSED: per-bucket LDS sort + lockstep seg-major gather ----------
// grid = B blocks x 512 thr (8 waves); wave owns 4 rows; 4-seg outer loop.
// Records sorted into 16KB LDS once; gather reads via uniform ds_read.
#define GREC(RK)                                                               \
    { const unsigned int p_ = *reinterpret_cast<const unsigned int*>(          \
          xh + (size_t)((RK)&0xFFFFu) * D_DIM + lane * 2);                     \
      const float v_ = __uint_as_float((RK)&0xFFFF0000u);                      \
      const __half2 h2_ = *reinterpret_cast<const __half2*>(&p_);              \
      ax += v_ * __half2float(h2_.x);                                          \
      ay += v_ * __half2float(h2_.y); }

__global__ __launch_bounds__(512) void sortgather_kernel(
    const unsigned short* __restrict__ xh, const int* __restrict__ boff,
    const ull* __restrict__ records, float* __restrict__ out, int N, int B)
{
    __shared__ int h[NB];
    __shared__ int cur[NB];
    __shared__ int boffL[NB + 1];
    __shared__ int wsum[2];
    __shared__ int woff[2];
    __shared__ unsigned int lrec[LREC_CAP];        // 16 KB sorted records

    const int tid  = (int)threadIdx.x;
    const int lane = tid & 63;
    const int w    = tid >> 6;                     // 0..7
    const int bkt  = blockIdx.x;
    const int start = boff[bkt], end = boff[bkt + 1];
    const int len   = end - start;
    const int rl0   = w * 4;                       // this wave's 4 rows

    float accx[4], accy[4];
    #pragma unroll
    for (int q = 0; q < 4; ++q) { accx[q] = 0.f; accy[q] = 0.f; }

    if (len > LREC_CAP) {
        // correctness fallback (statistically never): ballot-filter from global
        for (int c = start; c < end; c += 64) {
            const int idx = c + lane;
            unsigned int lo = 0xFFFFFFFFu, hi = 0;
            if (idx < end) {
                const ull r = records[idx];
                lo = (unsigned int)r;
                hi = (unsigned int)(r >> 32);
            }
            const int rl = (int)((lo >> 16) & (RPB - 1));
            ull mask = __ballot(idx < end && (rl >> 2) == w);
            while (mask) {
                const int jb = __ffsll(mask) - 1;
                mask &= mask - 1;
                const unsigned int lj = __shfl(lo, jb);
                const float v = __uint_as_float(__shfl(hi, jb));
                const unsigned int col = lj & 0xFFFFu;
                const unsigned int p = *reinterpret_cast<const unsigned int*>(
                    xh + (size_t)col * D_DIM + lane * 2);
                const __half2 h2 = *reinterpret_cast<const __half2*>(&p);
                const float px = __half2float(h2.x);
                const float py = __half2float(h2.y);
                const int q = (int)((lj >> 16) & 3u);
                if      (q == 0) { accx[0] += v * px; accy[0] += v * py; }
                else if (q == 1) { accx[1] += v * px; accy[1] += v * py; }
                else if (q == 2) { accx[2] += v * px; accy[2] += v * py; }
                else             { accx[3] += v * px; accy[3] += v * py; }
            }
        }
    } else {
        // ---- phase 1: histogram (global records -> LDS bins) ----
        if (tid < NB) h[tid] = 0;
        __syncthreads();
        for (int i = start + tid; i < end; i += 512) {
            const unsigned int lo = (unsigned int)records[i];
            const int bin = (int)((lo >> 16) << 2)
                          | (int)((lo & 0xFFFFu) >> CSEG_SHIFT);
            atomicAdd(&h[bin], 1);
        }
        __syncthreads();
        // ---- phase 2: exclusive scan over 128 bins (2-wave shfl scan) ----
        if (tid < NB) {
            const int v = h[tid];
            int incl = v;
            #pragma unroll
            for (int o = 1; o < 64; o <<= 1) {
                const int t = __shfl_up(incl, o);
                if (lane >= o) incl += t;
            }
            if (lane == 63) wsum[w] = incl;
            __syncthreads();
            if (tid == 0) { woff[0] = 0; woff[1] = wsum[0]; }
            __syncthreads();
            const int excl = woff[w] + incl - v;   // LDS-local offset
            cur[tid] = excl;
            boffL[tid] = excl;
        } else {
            __syncthreads();
            __syncthreads();
        }
        if (tid == 0) boffL[NB] = len;
        __syncthreads();
        // ---- phase 3: rank-scatter into LDS (4B records) ----
        for (int i = start + tid; i < end; i += 512) {
            const ull r = records[i];
            const unsigned int lo = (unsigned int)r;
            const int bin = (int)((lo >> 16) << 2)
                          | (int)((lo & 0xFFFFu) >> CSEG_SHIFT);
            const int pos = atomicAdd(&cur[bin], 1);
            lrec[pos] = (lo & 0xFFFFu)
                | ((unsigned int)f2bf(__uint_as_float((unsigned int)(r >> 32))) << 16);
        }
        __syncthreads();
        // ---- phase 4: lockstep seg-major gather from LDS ----
        for (int seg = 0; seg < CSEG; ++seg) {
            #pragma unroll
            for (int q = 0; q < 4; ++q) {
                const int bin = (rl0 + q) * CSEG + seg;
                int j        = boffL[bin];
                const int je = boffL[bin + 1];
                float ax = accx[q], ay = accy[q];
                for (; j + 15 < je; j += 16) {     // 16 x-loads in flight
                    const unsigned int r0  = lrec[j];
                    const unsigned int r1  = lrec[j + 1];
                    const unsigned int r2  = lrec[j + 2];
                    const unsigned int r3  = lrec[j + 3];
                    const unsigned int r4  = lrec[j + 4];
                    const unsigned int r5  = lrec[j + 5];
                    const unsigned int r6  = lrec[j + 6];
                    const unsigned int r7  = lrec[j + 7];
                    const unsigned int r8  = lrec[j + 8];
                    const unsigned int r9  = lrec[j + 9];
                    const unsigned int r10 = lrec[j + 10];
                    const unsigned int r11 = lrec[j + 11];
                    const unsigned int r12 = lrec[j + 12];
                    const unsigned int r13 = lrec[j + 13];
                    const unsigned int r14 = lrec[j + 14];
                    const unsigned int r15 = lrec[j + 15];
                    GREC(r0)  GREC(r1)  GREC(r2)  GREC(r3)
                    GREC(r4)  GREC(r5)  GREC(r6)  GREC(r7)
                    GREC(r8)  GREC(r9)  GREC(r10) GREC(r11)
                    GREC(r12) GREC(r13) GREC(r14) GREC(r15)
                }
                if (j + 7 < je) {
                    const unsigned int r0 = lrec[j];
                    const unsigned int r1 = lrec[j + 1];
                    const unsigned int r2 = lrec[j + 2];
                    const unsigned int r3 = lrec[j + 3];
                    const unsigned int r4 = lrec[j + 4];
                    const unsigned int r5 = lrec[j + 5];
                    const unsigned int r6 = lrec[j + 6];
                    const unsigned int r7 = lrec[j + 7];
                    GREC(r0) GREC(r1) GREC(r2) GREC(r3)
                    GREC(r4) GREC(r5) GREC(r6) GREC(r7)
                    j += 8;
                }
                if (j + 3 < je) {
                    const unsigned int r0 = lrec[j];
                    const unsigned int r1 = lrec[j + 1];
                    const unsigned int r2 = lrec[j + 2];
                    const unsigned int r3 = lrec[j + 3];
                    GREC(r0) GREC(r1) GREC(r2) GREC(r3)
                    j += 4;
                }
                if (j + 1 < je) {
                    const unsigned int r0 = lrec[j];
                    const unsigned int r1 = lrec[j + 1];
                    GREC(r0) GREC(r1)
                    j += 2;
                }
                if (j < je) {
                    const unsigned int r0 = lrec[j];
                    GREC(r0)
                }
                accx[q] = ax; accy[q] = ay;
            }
        }
    }

    const int row0 = (bkt << RPB_SHIFT) + rl0;
    #pragma unroll
    for (int q = 0; q < 4; ++q) {
        const int row = row0 + q;
        if (row < N)
            __builtin_nontemporal_store(pack2f(accx[q], accy[q]),
                reinterpret_cast<ull*>(out + (size_t)row * D_DIM + lane * 2));
    }
}

extern "C" void kernel_launch(void* const* d_in, const int* in_sizes, int n_in,
                              void* d_out, int out_size, void* d_ws, size_t ws_size,
                              hipStream_t stream)
{
    const float* x         = (const float*)d_in[0];
    const float* edge_vals = (const float*)d_in[1];
    const float* ws        = (const float*)d_in[2];
    const int*   edge_rows = (const int*)d_in[3];
    const int*   edge_cols = (const int*)d_in[4];
    float*       out       = (float*)d_out;

    const int num_op = in_sizes[2];               // 8
    const int E      = in_sizes[1] / num_op;      // 400000
    const int N      = in_sizes[0] / D_DIM;       // 50000
    const long Etot  = (long)num_op * (long)E;    // 3.2M
    const int  B     = (N + RPB - 1) / RPB;       // 1563 buckets
    const float inv_num = 1.0f / (float)num_op;

    // workspace: boff | gcursor | xh | records
    const size_t off_boff    = 0;
    const size_t off_gcur    = ((size_t)(B + 1) * 4 + 255) & ~(size_t)255;
    const size_t off_xh      = (off_gcur + (size_t)B * 4 + 255) & ~(size_t)255;
    const size_t off_records = (off_xh + (size_t)N * D_DIM * 2 + 255) & ~(size_t)255;
    const size_t need        = off_records + (size_t)Etot * 8;

    if (ws_size < need || B > MAXB || N > 65535) {
        (void)hipMemsetAsync(d_out, 0, (size_t)out_size * sizeof(float), stream);
        dim3 grid(256, num_op, 1);
        spmm_scatter_kernel<<<grid, 256, 0, stream>>>(
            x, edge_vals, ws, edge_rows, edge_cols, out, E, inv_num);
        return;
    }

    int* boff    = (int*)((char*)d_ws + off_boff);
    int* gcursor = (int*)((char*)d_ws + off_gcur);
    unsigned short* xh = (unsigned short*)((char*)d_ws + off_xh);
    ull* records = (ull*)((char*)d_ws + off_records);

    (void)hipMemsetAsync(gcursor, 0, (size_t)B * 4, stream);

    convert_count_kernel<<<CVT_BLOCKS + CNT_BLOCKS, 256, 0, stream>>>(
        (const float4*)x, (ull*)xh, N * D_DIM / 4, edge_rows, gcursor, Etot, B);
    scan_kernel<<<1, SCAN_BLOCK, 0, stream>>>(gcursor, boff, B);

    dim3 sgrid((E + CHUNK - 1) / CHUNK, num_op, 1);   // 49 x 8 = 392 blocks, 16 waves
    scatter_bucket_kernel<<<sgrid, 1024, 0, stream>>>(
        edge_rows, edge_cols, edge_vals, ws, gcursor, records, E, inv_num, B);

    sortgather_kernel<<<B, 512, 0, stream>>>(xh, boff, records, out, N, B);
}